// Round 4
// baseline (375.104 us; speedup 1.0000x reference)
//
#include <hip/hip_runtime.h>
#include <math.h>

#define N_ 8
#define C_ 8
#define F_ 257
#define T_ 1000
#define ATT_ 512
#define NF_ (N_*F_)
#define TSPLIT_ 4
#define TCHUNK_ 250
#define EPSILON_ 1.1920928955078125e-07f
#define EPS_ 1e-5f

__device__ inline float2 cmul(float2 a, float2 b){
  return make_float2(a.x*b.x - a.y*b.y, a.x*b.y + a.y*b.x);
}
__device__ inline float2 crecip(float2 a){
  float id = 1.0f/(a.x*a.x + a.y*a.y);
  return make_float2(a.x*id, -a.y*id);
}
__device__ inline float2 cdivz(float2 a, float2 b){
  float id = 1.0f/(b.x*b.x + b.y*b.y);
  return make_float2((a.x*b.x + a.y*b.y)*id, (a.y*b.x - a.x*b.y)*id);
}
__device__ inline float2 shfl2(float2 v, int src){
  return make_float2(__shfl(v.x, src, 64), __shfl(v.y, src, 64));
}

// K1a: per (n,f): max over t of |mask|, and sum of normalized mask m = mask/(max+eps)
__global__ __launch_bounds__(256) void k1a_stats(
    const float* __restrict__ mask, float* __restrict__ maxv, float* __restrict__ summ)
{
  __shared__ float smx[8][33];
  __shared__ float ssm[8][33];
  const int n = blockIdx.y;
  const int f0 = blockIdx.x*32;
  const int tx = threadIdx.x, ty = threadIdx.y;
  const int f = f0 + tx;
  float mx = 0.f, sm = 0.f;
  if (f < F_){
    for (int t = ty; t < T_; t += 8){
      float v = mask[((size_t)n*T_ + t)*F_ + f];
      mx = fmaxf(mx, fabsf(v));
      sm += v;
    }
  }
  smx[ty][tx] = mx; ssm[ty][tx] = sm;
  __syncthreads();
  if (ty == 0 && f < F_){
    #pragma unroll
    for (int k=1;k<8;++k){ mx = fmaxf(mx, smx[k][tx]); sm += ssm[k][tx]; }
    maxv[n*F_ + f] = mx;
    summ[n*F_ + f] = sm/(mx + EPSILON_);
  }
}

// K1b: normalized mask transpose (n,t,f) -> m_t (n,f,t)
__global__ __launch_bounds__(256) void k1b_transpose(
    const float* __restrict__ mask, const float* __restrict__ maxv, float* __restrict__ m_t)
{
  __shared__ float tile[32][33];
  const int n = blockIdx.z;
  const int f0 = blockIdx.y*32;
  const int t0 = blockIdx.x*32;
  const int tx = threadIdx.x, ty = threadIdx.y;
  const int f = f0 + tx;
  float inv = 0.f;
  if (f < F_) inv = 1.0f/(maxv[n*F_ + f] + EPSILON_);
  #pragma unroll
  for (int k=0;k<4;++k){
    const int tl = ty + 8*k;
    const int t = t0 + tl;
    float v = 0.f;
    if (f < F_ && t < T_) v = mask[((size_t)n*T_ + t)*F_ + f];
    tile[tl][tx] = v*inv;
  }
  __syncthreads();
  #pragma unroll
  for (int k=0;k<4;++k){
    const int fl = ty + 8*k;
    const int f2 = f0 + fl, t2 = t0 + tx;
    if (f2 < F_ && t2 < T_) m_t[((size_t)n*F_ + f2)*T_ + t2] = tile[tx][fl];
  }
}

// K2: partial covariance accumulators. blockIdx.x = nf, blockIdx.y = t-chunk (250 t's).
// Per lane 64 scalars, entry e = type*16 + r*8 + j (type: 0=tr 1=ti 2=sr 3=si; row = 2*wave + r).
// Tree-reduce leaves lane l holding total for entry l; coalesced store to part[].
__global__ __launch_bounds__(256) void k2_covar(
    const float* __restrict__ xre, const float* __restrict__ xim,
    const float* __restrict__ m_t, float* __restrict__ part)
{
  __shared__ float s_re[C_][256];
  __shared__ float s_im[C_][256];
  __shared__ float s_m[256];
  const int nf = blockIdx.x;
  const int tc = blockIdx.y;
  const int n = nf / F_;
  const int f = nf % F_;
  const int tid = threadIdx.x;
  const int wave = tid >> 6;
  const int lane = tid & 63;
  const int r0 = wave*2;
  const int tbase = tc*TCHUNK_;

  const int tt = lane*4;
  #pragma unroll
  for (int ci=0; ci<2; ++ci){
    const int c = r0 + ci;
    const size_t base = (((size_t)n*C_ + c)*F_ + f)*T_ + tbase + tt;
    if (tt + 3 < TCHUNK_){
      *(float4*)&s_re[c][tt] = *(const float4*)(xre + base);
      *(float4*)&s_im[c][tt] = *(const float4*)(xim + base);
    } else {
      #pragma unroll
      for (int e=0;e<4;++e){
        const bool ok = (tt + e) < TCHUNK_;
        s_re[c][tt+e] = ok ? xre[base+e] : 0.f;
        s_im[c][tt+e] = ok ? xim[base+e] : 0.f;
      }
    }
  }
  if (wave == 0){
    const size_t mb = (size_t)nf*T_ + tbase + tt;
    if (tt + 3 < TCHUNK_){
      *(float4*)&s_m[tt] = *(const float4*)(m_t + mb);
    } else {
      #pragma unroll
      for (int e=0;e<4;++e) s_m[tt+e] = ((tt+e) < TCHUNK_) ? m_t[mb+e] : 0.f;
    }
  }
  __syncthreads();

  float v[64];
  #pragma unroll
  for (int e=0;e<64;++e) v[e] = 0.f;

  #pragma unroll
  for (int ti=0; ti<4; ++ti){
    const int t = ti*64 + lane;
    const float mm = s_m[t];
    const float a0r = s_re[r0][t],   a0i = s_im[r0][t];
    const float a1r = s_re[r0+1][t], a1i = s_im[r0+1][t];
    #pragma unroll
    for (int j=0;j<8;++j){
      const float br = s_re[j][t], bi = s_im[j][t];
      float pr = a0r*br + a0i*bi;
      float pi = a0i*br - a0r*bi;
      v[j]    += pr;     v[16+j] += pi;
      v[32+j] += mm*pr;  v[48+j] += mm*pi;
      pr = a1r*br + a1i*bi;
      pi = a1i*br - a1r*bi;
      v[8+j]  += pr;     v[24+j] += pi;
      v[40+j] += mm*pr;  v[56+j] += mm*pi;
    }
  }

  // paired-fold tree reduce: after step with stride S, v[k] holds sums over lane-groups,
  // final: lane l holds total of entry l. In-place safe (reads v[2k],v[2k+1] before write v[k]).
  #define RSTEP(S, CNT) \
    _Pragma("unroll") \
    for (int k=0;k<CNT;++k){ \
      const float a = v[2*k], b = v[2*k+1]; \
      const bool hi = (lane & S) != 0; \
      const float mine = hi ? b : a; \
      const float oth  = hi ? a : b; \
      v[k] = mine + __shfl_xor(oth, S, 64); \
    }
  RSTEP(1,32) RSTEP(2,16) RSTEP(4,8) RSTEP(8,4) RSTEP(16,2) RSTEP(32,1)
  #undef RSTEP

  part[(((size_t)tc*NF_ + nf)*4 + wave)*64 + lane] = v[0];
}

// K2r: reduce the 4 t-chunk partials, normalize -> Rs, Rn. One wave per nf, lane=(i,j).
__global__ __launch_bounds__(64) void k2r_reduce(
    const float* __restrict__ part, const float* __restrict__ summ,
    float2* __restrict__ Rs, float2* __restrict__ Rn)
{
  const int nf = blockIdx.x;
  const int lane = threadIdx.x;
  const int i = lane >> 3, j = lane & 7;
  const int w = i >> 1, r = i & 1;
  float tr=0.f, ti=0.f, sr=0.f, si=0.f;
  #pragma unroll
  for (int tc=0; tc<TSPLIT_; ++tc){
    const float* p = part + (((size_t)tc*NF_ + nf)*4 + w)*64;
    tr += p[ 0 + r*8 + j];
    ti += p[16 + r*8 + j];
    sr += p[32 + r*8 + j];
    si += p[48 + r*8 + j];
  }
  const float sm = summ[nf];
  const float ids = 1.0f/fmaxf(sm, EPSILON_);
  const float idn = 1.0f/fmaxf((float)T_ - sm, EPSILON_);
  Rs[(size_t)nf*64 + lane] = make_float2(sr*ids, si*ids);
  Rn[(size_t)nf*64 + lane] = make_float2((tr-sr)*idn + ((i==j)?EPS_:0.f), (ti-si)*idn);
}

// K3a: feat[nc][f] = |mean offdiag of Rs row c| ; also zero the gate accumulators g[64]
__global__ __launch_bounds__(256) void k3a_feat(
    const float2* __restrict__ Rs, float* __restrict__ feat, float* __restrict__ g)
{
  const int nc = blockIdx.x;
  const int n = nc >> 3, c = nc & 7;
  const int tid = threadIdx.x;
  if (nc == 0 && tid < N_*C_) g[tid] = 0.f;
  for (int f = tid; f < F_; f += 256){
    const float2* row = Rs + (((size_t)n*F_ + f)*8 + c)*8;
    float sr = 0.f, si = 0.f;
    #pragma unroll
    for (int j=0;j<8;++j){ float2 v = row[j]; sr += v.x; si += v.y; }
    float2 d = row[c];
    sr = (sr - d.x)*(1.0f/7.0f);
    si = (si - d.y)*(1.0f/7.0f);
    feat[(size_t)nc*F_ + f] = sqrtf(sr*sr + si*si);
  }
}

// K3b: g[nc] += sum_a tanh(feat[nc,:] . proj_w[a,:] + proj_b[a]) * gvec_w[a]
__global__ __launch_bounds__(256) void k3b_proj(
    const float* __restrict__ feat, const float* __restrict__ proj_w,
    const float* __restrict__ proj_b, const float* __restrict__ gvec_w,
    float* __restrict__ g)
{
  const int nc = blockIdx.y;
  const int tid = threadIdx.x;
  const int wave = tid >> 6, lane = tid & 63;
  const int a0 = blockIdx.x*16 + wave*4;
  float acc0 = 0.f, acc1 = 0.f, acc2 = 0.f, acc3 = 0.f;
  const float* fr = feat + (size_t)nc*F_;
  const float* w0 = proj_w + (size_t)(a0+0)*F_;
  const float* w1 = proj_w + (size_t)(a0+1)*F_;
  const float* w2 = proj_w + (size_t)(a0+2)*F_;
  const float* w3 = proj_w + (size_t)(a0+3)*F_;
  for (int fi = lane; fi < F_; fi += 64){
    const float fv = fr[fi];
    acc0 += fv*w0[fi];
    acc1 += fv*w1[fi];
    acc2 += fv*w2[fi];
    acc3 += fv*w3[fi];
  }
  #pragma unroll
  for (int s=1;s<64;s<<=1){
    acc0 += __shfl_xor(acc0, s, 64);
    acc1 += __shfl_xor(acc1, s, 64);
    acc2 += __shfl_xor(acc2, s, 64);
    acc3 += __shfl_xor(acc3, s, 64);
  }
  if (lane == 0){
    float v = tanhf(acc0 + proj_b[a0+0])*gvec_w[a0+0]
            + tanhf(acc1 + proj_b[a0+1])*gvec_w[a0+1]
            + tanhf(acc2 + proj_b[a0+2])*gvec_w[a0+2]
            + tanhf(acc3 + proj_b[a0+3])*gvec_w[a0+3];
    atomicAdd(&g[nc], v);
  }
}

// K4: one wave per (n,f): softmax(u), invert Rn, w = Rn^-1 (Rs u) / (tr(Rn^-1 Rs)+EPS)
__global__ __launch_bounds__(256) void k4_solve(
    const float2* __restrict__ Rs, const float2* __restrict__ Rn,
    const float* __restrict__ g, float2* __restrict__ w_ws)
{
  const int tid = threadIdx.x;
  const int wid = blockIdx.x*4 + (tid >> 6);
  const int lane = tid & 63;
  const int ii = lane >> 3, jj = lane & 7;
  const int n = wid / F_;
  float2 A = Rn[(size_t)wid*64 + lane];
  float2 R = Rs[(size_t)wid*64 + lane];
  float gv = g[n*C_ + jj];
  float mx = gv;
  #pragma unroll
  for (int s=1;s<8;s<<=1) mx = fmaxf(mx, __shfl_xor(mx, s, 64));
  float e = expf(gv - mx);
  float es = e;
  #pragma unroll
  for (int s=1;s<8;s<<=1) es += __shfl_xor(es, s, 64);
  const float u = e / es;
  #pragma unroll
  for (int k=0;k<8;++k){
    float2 piv    = shfl2(A, k*9);
    float2 oldAkj = shfl2(A, k*8 + jj);
    float2 dum    = shfl2(A, ii*8 + k);
    float2 pinv = crecip(piv);
    float2 newk = (jj==k) ? pinv : cmul(oldAkj, pinv);
    if (ii == k){
      A = newk;
    } else {
      float2 b = (jj==k) ? make_float2(0.f,0.f) : A;
      float2 t = cmul(newk, dum);
      A = make_float2(b.x - t.x, b.y - t.y);
    }
  }
  float2 v = make_float2(R.x*u, R.y*u);
  #pragma unroll
  for (int s=1;s<8;s<<=1){ v.x += __shfl_xor(v.x, s, 64); v.y += __shfl_xor(v.y, s, 64); }
  float2 Rt = shfl2(R, jj*8 + ii);
  float2 tp = cmul(A, Rt);
  #pragma unroll
  for (int s=1;s<64;s<<=1){ tp.x += __shfl_xor(tp.x, s, 64); tp.y += __shfl_xor(tp.y, s, 64); }
  tp.x += EPS_;
  float2 vj = shfl2(v, jj*8);
  float2 q = cmul(A, vj);
  #pragma unroll
  for (int s=1;s<8;s<<=1){ q.x += __shfl_xor(q.x, s, 64); q.y += __shfl_xor(q.y, s, 64); }
  float2 wv = cdivz(q, tp);
  if (jj == 0) w_ws[(size_t)wid*8 + ii] = wv;
}

// K5: beam[n,t,f] = sum_c conj(w[n,f,c]) * x[n,c,f,t]; output (n,t,f,2) via LDS transpose
__global__ __launch_bounds__(256) void k5_beam(
    const float* __restrict__ xre, const float* __restrict__ xim,
    const float2* __restrict__ w_ws, float* __restrict__ out)
{
  __shared__ float b_re[32][129];
  __shared__ float b_im[32][129];
  __shared__ float2 w_l[32][8];
  const int n = blockIdx.z;
  const int f0 = blockIdx.y*32;
  const int t0 = blockIdx.x*128;
  const int tid = threadIdx.x;
  {
    const int fl = tid >> 3, c = tid & 7;
    const int f = f0 + fl;
    w_l[fl][c] = (f < F_) ? w_ws[((size_t)n*F_ + f)*8 + c] : make_float2(0.f,0.f);
  }
  __syncthreads();
  const int tq = (tid & 31)*4;
  const int fg = tid >> 5;
  const int t = t0 + tq;
  const bool tok = (t + 3) < T_;
  #pragma unroll
  for (int fi=0; fi<4; ++fi){
    const int fl = fg + fi*8;
    const int f = f0 + fl;
    float4 ar = make_float4(0,0,0,0), ai = make_float4(0,0,0,0);
    if (f < F_ && tok){
      #pragma unroll
      for (int c=0;c<8;++c){
        const size_t base = (((size_t)n*C_ + c)*F_ + f)*T_ + t;
        const float4 xr = *(const float4*)(xre + base);
        const float4 xi = *(const float4*)(xim + base);
        const float2 wv = w_l[fl][c];
        ar.x += wv.x*xr.x + wv.y*xi.x;  ai.x += wv.x*xi.x - wv.y*xr.x;
        ar.y += wv.x*xr.y + wv.y*xi.y;  ai.y += wv.x*xi.y - wv.y*xr.y;
        ar.z += wv.x*xr.z + wv.y*xi.z;  ai.z += wv.x*xi.z - wv.y*xr.z;
        ar.w += wv.x*xr.w + wv.y*xi.w;  ai.w += wv.x*xi.w - wv.y*xr.w;
      }
    }
    b_re[fl][tq+0]=ar.x; b_re[fl][tq+1]=ar.y; b_re[fl][tq+2]=ar.z; b_re[fl][tq+3]=ar.w;
    b_im[fl][tq+0]=ai.x; b_im[fl][tq+1]=ai.y; b_im[fl][tq+2]=ai.z; b_im[fl][tq+3]=ai.w;
  }
  __syncthreads();
  const int fl2 = tid & 31;
  const int tp = tid >> 5;
  const int f2 = f0 + fl2;
  if (f2 < F_){
    #pragma unroll
    for (int k=0;k<16;++k){
      const int tl = tp + k*8;
      const int t2 = t0 + tl;
      if (t2 < T_){
        float2 v = make_float2(b_re[fl2][tl], b_im[fl2][tl]);
        *(float2*)(out + (((size_t)n*T_ + t2)*F_ + f2)*2) = v;
      }
    }
  }
}

extern "C" void kernel_launch(void* const* d_in, const int* in_sizes, int n_in,
                              void* d_out, int out_size, void* d_ws, size_t ws_size,
                              hipStream_t stream)
{
  const float* mask   = (const float*)d_in[0];
  const float* xre    = (const float*)d_in[1];
  const float* xim    = (const float*)d_in[2];
  const float* proj_w = (const float*)d_in[3];
  const float* proj_b = (const float*)d_in[4];
  const float* gvec_w = (const float*)d_in[5];
  const float* gvec_b = (const float*)d_in[6];
  (void)gvec_b;
  float* out = (float*)d_out;
  char* ws = (char*)d_ws;

  size_t o = 0;
  auto alloc = [&](size_t bytes){ size_t r = o; o += (bytes + 255) & ~(size_t)255; return r; };
  float*  m_t  = (float*) (ws + alloc((size_t)N_*F_*T_*4));
  float*  maxv = (float*) (ws + alloc((size_t)N_*F_*4));
  float*  summ = (float*) (ws + alloc((size_t)N_*F_*4));
  float2* Rs   = (float2*)(ws + alloc((size_t)NF_*64*8));
  float2* Rn   = (float2*)(ws + alloc((size_t)NF_*64*8));
  float*  part = (float*) (ws + alloc((size_t)TSPLIT_*NF_*4*64*4));
  float*  g    = (float*) (ws + alloc((size_t)N_*C_*4));
  float*  feat = (float*) (ws + alloc((size_t)N_*C_*F_*4));
  float2* w_ws = (float2*)(ws + alloc((size_t)NF_*C_*8));

  k1a_stats    <<<dim3(9, N_),        dim3(32,8), 0, stream>>>(mask, maxv, summ);
  k1b_transpose<<<dim3(32, 9, N_),    dim3(32,8), 0, stream>>>(mask, maxv, m_t);
  k2_covar     <<<dim3(NF_, TSPLIT_), dim3(256),  0, stream>>>(xre, xim, m_t, part);
  k2r_reduce   <<<dim3(NF_),          dim3(64),   0, stream>>>(part, summ, Rs, Rn);
  k3a_feat     <<<dim3(N_*C_),        dim3(256),  0, stream>>>(Rs, feat, g);
  k3b_proj     <<<dim3(32, N_*C_),    dim3(256),  0, stream>>>(feat, proj_w, proj_b, gvec_w, g);
  k4_solve     <<<dim3(NF_/4),        dim3(256),  0, stream>>>(Rs, Rn, g, w_ws);
  k5_beam      <<<dim3(8, 9, N_),     dim3(256),  0, stream>>>(xre, xim, w_ws, out);
}

// Round 5
// 327.056 us; speedup vs baseline: 1.1469x; 1.1469x over previous
//
#include <hip/hip_runtime.h>
#include <math.h>

#define N_ 8
#define C_ 8
#define F_ 257
#define T_ 1000
#define ATT_ 512
#define NF_ (N_*F_)
#define TSPLIT_ 4
#define EPSILON_ 1.1920928955078125e-07f
#define EPS_ 1e-5f

__device__ inline float2 cmul(float2 a, float2 b){
  return make_float2(a.x*b.x - a.y*b.y, a.x*b.y + a.y*b.x);
}
__device__ inline float2 crecip(float2 a){
  float id = 1.0f/(a.x*a.x + a.y*a.y);
  return make_float2(a.x*id, -a.y*id);
}
__device__ inline float2 cdivz(float2 a, float2 b){
  float id = 1.0f/(b.x*b.x + b.y*b.y);
  return make_float2((a.x*b.x + a.y*b.y)*id, (a.y*b.x - a.x*b.y)*id);
}
__device__ inline float2 shfl2(float2 v, int src){
  return make_float2(__shfl(v.x, src, 64), __shfl(v.y, src, 64));
}

// K1a: per (n,f): max over t of |mask|, and sum of normalized mask m = mask/(max+eps)
__global__ __launch_bounds__(256) void k1a_stats(
    const float* __restrict__ mask, float* __restrict__ maxv, float* __restrict__ summ)
{
  __shared__ float smx[8][33];
  __shared__ float ssm[8][33];
  const int n = blockIdx.y;
  const int f0 = blockIdx.x*32;
  const int tx = threadIdx.x, ty = threadIdx.y;
  const int f = f0 + tx;
  float mx = 0.f, sm = 0.f;
  if (f < F_){
    for (int t = ty; t < T_; t += 8){
      float v = mask[((size_t)n*T_ + t)*F_ + f];
      mx = fmaxf(mx, fabsf(v));
      sm += v;
    }
  }
  smx[ty][tx] = mx; ssm[ty][tx] = sm;
  __syncthreads();
  if (ty == 0 && f < F_){
    #pragma unroll
    for (int k=1;k<8;++k){ mx = fmaxf(mx, smx[k][tx]); sm += ssm[k][tx]; }
    maxv[n*F_ + f] = mx;
    summ[n*F_ + f] = sm/(mx + EPSILON_);
  }
}

// K1b: normalized mask transpose (n,t,f) -> m_t (n,f,t)
__global__ __launch_bounds__(256) void k1b_transpose(
    const float* __restrict__ mask, const float* __restrict__ maxv, float* __restrict__ m_t)
{
  __shared__ float tile[32][33];
  const int n = blockIdx.z;
  const int f0 = blockIdx.y*32;
  const int t0 = blockIdx.x*32;
  const int tx = threadIdx.x, ty = threadIdx.y;
  const int f = f0 + tx;
  float inv = 0.f;
  if (f < F_) inv = 1.0f/(maxv[n*F_ + f] + EPSILON_);
  #pragma unroll
  for (int k=0;k<4;++k){
    const int tl = ty + 8*k;
    const int t = t0 + tl;
    float v = 0.f;
    if (f < F_ && t < T_) v = mask[((size_t)n*T_ + t)*F_ + f];
    tile[tl][tx] = v*inv;
  }
  __syncthreads();
  #pragma unroll
  for (int k=0;k<4;++k){
    const int fl = ty + 8*k;
    const int f2 = f0 + fl, t2 = t0 + tx;
    if (f2 < F_ && t2 < T_) m_t[((size_t)n*F_ + f2)*T_ + t2] = tile[tx][fl];
  }
}

// K2: one wave per (nf, t-chunk). Global->register loads, Hermitian-triangle accumulate.
// Chunks: [0,256),[256,512),[512,768),[768,1000). Lane handles t = tbase + 4*lane .. +3.
// 128 accumulator entries: e=2d+{0:tot,1:masked} for diagonals d=0..7 (real);
// e=16+4p+{0:tr,1:ti,2:sr,3:si} for off-diag pairs p(a,b)=a*(13-a)/2+b-1 (a<b).
// Paired-fold tree reduce over two 64-entry groups -> lane l holds e=l and e=64+l.
__global__ __launch_bounds__(64, 2) void k2_covar(
    const float* __restrict__ xre, const float* __restrict__ xim,
    const float* __restrict__ m_t, float* __restrict__ part)
{
  const int nf = blockIdx.x;
  const int tc = blockIdx.y;
  const int n = nf / F_;
  const int f = nf % F_;
  const int lane = threadIdx.x;
  const int tbase = tc*256;
  const int nt = (tc == 3) ? (T_ - 768) : 256;   // 232 on last chunk, all multiples of 4
  const int tq = lane*4;
  const bool act = tq < nt;

  float xr[8][4], xi[8][4], mm[4];
  if (act){
    const float4 m4 = *(const float4*)(m_t + (size_t)nf*T_ + tbase + tq);
    mm[0]=m4.x; mm[1]=m4.y; mm[2]=m4.z; mm[3]=m4.w;
    #pragma unroll
    for (int c=0;c<8;++c){
      const size_t base = (((size_t)n*C_ + c)*F_ + f)*T_ + tbase + tq;
      const float4 r4 = *(const float4*)(xre + base);
      const float4 i4 = *(const float4*)(xim + base);
      xr[c][0]=r4.x; xr[c][1]=r4.y; xr[c][2]=r4.z; xr[c][3]=r4.w;
      xi[c][0]=i4.x; xi[c][1]=i4.y; xi[c][2]=i4.z; xi[c][3]=i4.w;
    }
  } else {
    mm[0]=mm[1]=mm[2]=mm[3]=0.f;
    #pragma unroll
    for (int c=0;c<8;++c){
      #pragma unroll
      for (int q=0;q<4;++q){ xr[c][q]=0.f; xi[c][q]=0.f; }
    }
  }

  float v[128];
  #pragma unroll
  for (int e=0;e<128;++e) v[e] = 0.f;

  #pragma unroll
  for (int q=0;q<4;++q){
    const float m = mm[q];
    #pragma unroll
    for (int d=0;d<8;++d){
      const float p = xr[d][q]*xr[d][q] + xi[d][q]*xi[d][q];
      v[2*d]   += p;
      v[2*d+1] += m*p;
    }
    #pragma unroll
    for (int a=0;a<8;++a){
      #pragma unroll
      for (int b=a+1;b<8;++b){
        const int e = 16 + 4*(a*(13-a)/2 + b - 1);
        const float pr = xr[a][q]*xr[b][q] + xi[a][q]*xi[b][q];
        const float pi = xi[a][q]*xr[b][q] - xr[a][q]*xi[b][q];
        v[e]   += pr;   v[e+1] += pi;
        v[e+2] += m*pr; v[e+3] += m*pi;
      }
    }
  }

  // paired-fold tree reduce on each 64-entry group (in-place safe).
  #define RSTEP(S, CNT, OFF) \
    _Pragma("unroll") \
    for (int k=0;k<CNT;++k){ \
      const float a_ = v[OFF+2*k], b_ = v[OFF+2*k+1]; \
      const bool hi = (lane & S) != 0; \
      const float mine = hi ? b_ : a_; \
      const float oth  = hi ? a_ : b_; \
      v[OFF+k] = mine + __shfl_xor(oth, S, 64); \
    }
  RSTEP(1,32,0) RSTEP(2,16,0) RSTEP(4,8,0) RSTEP(8,4,0) RSTEP(16,2,0) RSTEP(32,1,0)
  RSTEP(1,32,64) RSTEP(2,16,64) RSTEP(4,8,64) RSTEP(8,4,64) RSTEP(16,2,64) RSTEP(32,1,64)
  #undef RSTEP

  float* pp = part + ((size_t)tc*NF_ + nf)*128;
  pp[lane]      = v[0];
  pp[64 + lane] = v[64];
}

// K2r: sum the 4 t-chunk partials, reconstruct full Hermitian 8x8, normalize -> Rs, Rn.
__global__ __launch_bounds__(64) void k2r_reduce(
    const float* __restrict__ part, const float* __restrict__ summ,
    float2* __restrict__ Rs, float2* __restrict__ Rn)
{
  const int nf = blockIdx.x;
  const int lane = threadIdx.x;
  const int i = lane >> 3, j = lane & 7;
  const int a = (i < j) ? i : j;
  const int b = (i < j) ? j : i;
  const float sgn = (i <= j) ? 1.f : -1.f;
  const int eo = 16 + 4*(a*(13-a)/2 + b - 1);
  float tr=0.f, ti=0.f, sr=0.f, si=0.f;
  #pragma unroll
  for (int tc=0; tc<TSPLIT_; ++tc){
    const float* p = part + ((size_t)tc*NF_ + nf)*128;
    if (i == j){
      tr += p[2*i];
      sr += p[2*i+1];
    } else {
      tr += p[eo];
      ti += sgn*p[eo+1];
      sr += p[eo+2];
      si += sgn*p[eo+3];
    }
  }
  const float sm = summ[nf];
  const float ids = 1.0f/fmaxf(sm, EPSILON_);
  const float idn = 1.0f/fmaxf((float)T_ - sm, EPSILON_);
  Rs[(size_t)nf*64 + lane] = make_float2(sr*ids, si*ids);
  Rn[(size_t)nf*64 + lane] = make_float2((tr-sr)*idn + ((i==j)?EPS_:0.f), (ti-si)*idn);
}

// K3a: feat[nc][f] = |mean offdiag of Rs row c| ; also zero the gate accumulators g[64]
__global__ __launch_bounds__(256) void k3a_feat(
    const float2* __restrict__ Rs, float* __restrict__ feat, float* __restrict__ g)
{
  const int nc = blockIdx.x;
  const int n = nc >> 3, c = nc & 7;
  const int tid = threadIdx.x;
  if (nc == 0 && tid < N_*C_) g[tid] = 0.f;
  for (int f = tid; f < F_; f += 256){
    const float2* row = Rs + (((size_t)n*F_ + f)*8 + c)*8;
    float sr = 0.f, si = 0.f;
    #pragma unroll
    for (int j=0;j<8;++j){ float2 v = row[j]; sr += v.x; si += v.y; }
    float2 d = row[c];
    sr = (sr - d.x)*(1.0f/7.0f);
    si = (si - d.y)*(1.0f/7.0f);
    feat[(size_t)nc*F_ + f] = sqrtf(sr*sr + si*si);
  }
}

// K3b: g[nc] += sum_a tanh(feat[nc,:] . proj_w[a,:] + proj_b[a]) * gvec_w[a]
__global__ __launch_bounds__(256) void k3b_proj(
    const float* __restrict__ feat, const float* __restrict__ proj_w,
    const float* __restrict__ proj_b, const float* __restrict__ gvec_w,
    float* __restrict__ g)
{
  const int nc = blockIdx.y;
  const int tid = threadIdx.x;
  const int wave = tid >> 6, lane = tid & 63;
  const int a0 = blockIdx.x*16 + wave*4;
  float acc0 = 0.f, acc1 = 0.f, acc2 = 0.f, acc3 = 0.f;
  const float* fr = feat + (size_t)nc*F_;
  const float* w0 = proj_w + (size_t)(a0+0)*F_;
  const float* w1 = proj_w + (size_t)(a0+1)*F_;
  const float* w2 = proj_w + (size_t)(a0+2)*F_;
  const float* w3 = proj_w + (size_t)(a0+3)*F_;
  for (int fi = lane; fi < F_; fi += 64){
    const float fv = fr[fi];
    acc0 += fv*w0[fi];
    acc1 += fv*w1[fi];
    acc2 += fv*w2[fi];
    acc3 += fv*w3[fi];
  }
  #pragma unroll
  for (int s=1;s<64;s<<=1){
    acc0 += __shfl_xor(acc0, s, 64);
    acc1 += __shfl_xor(acc1, s, 64);
    acc2 += __shfl_xor(acc2, s, 64);
    acc3 += __shfl_xor(acc3, s, 64);
  }
  if (lane == 0){
    float v = tanhf(acc0 + proj_b[a0+0])*gvec_w[a0+0]
            + tanhf(acc1 + proj_b[a0+1])*gvec_w[a0+1]
            + tanhf(acc2 + proj_b[a0+2])*gvec_w[a0+2]
            + tanhf(acc3 + proj_b[a0+3])*gvec_w[a0+3];
    atomicAdd(&g[nc], v);
  }
}

// K4: one wave per (n,f): softmax(u), invert Rn, w = Rn^-1 (Rs u) / (tr(Rn^-1 Rs)+EPS)
__global__ __launch_bounds__(256) void k4_solve(
    const float2* __restrict__ Rs, const float2* __restrict__ Rn,
    const float* __restrict__ g, float2* __restrict__ w_ws)
{
  const int tid = threadIdx.x;
  const int wid = blockIdx.x*4 + (tid >> 6);
  const int lane = tid & 63;
  const int ii = lane >> 3, jj = lane & 7;
  const int n = wid / F_;
  float2 A = Rn[(size_t)wid*64 + lane];
  float2 R = Rs[(size_t)wid*64 + lane];
  float gv = g[n*C_ + jj];
  float mx = gv;
  #pragma unroll
  for (int s=1;s<8;s<<=1) mx = fmaxf(mx, __shfl_xor(mx, s, 64));
  float e = expf(gv - mx);
  float es = e;
  #pragma unroll
  for (int s=1;s<8;s<<=1) es += __shfl_xor(es, s, 64);
  const float u = e / es;
  #pragma unroll
  for (int k=0;k<8;++k){
    float2 piv    = shfl2(A, k*9);
    float2 oldAkj = shfl2(A, k*8 + jj);
    float2 dum    = shfl2(A, ii*8 + k);
    float2 pinv = crecip(piv);
    float2 newk = (jj==k) ? pinv : cmul(oldAkj, pinv);
    if (ii == k){
      A = newk;
    } else {
      float2 b = (jj==k) ? make_float2(0.f,0.f) : A;
      float2 t = cmul(newk, dum);
      A = make_float2(b.x - t.x, b.y - t.y);
    }
  }
  float2 v = make_float2(R.x*u, R.y*u);
  #pragma unroll
  for (int s=1;s<8;s<<=1){ v.x += __shfl_xor(v.x, s, 64); v.y += __shfl_xor(v.y, s, 64); }
  float2 Rt = shfl2(R, jj*8 + ii);
  float2 tp = cmul(A, Rt);
  #pragma unroll
  for (int s=1;s<64;s<<=1){ tp.x += __shfl_xor(tp.x, s, 64); tp.y += __shfl_xor(tp.y, s, 64); }
  tp.x += EPS_;
  float2 vj = shfl2(v, jj*8);
  float2 q = cmul(A, vj);
  #pragma unroll
  for (int s=1;s<8;s<<=1){ q.x += __shfl_xor(q.x, s, 64); q.y += __shfl_xor(q.y, s, 64); }
  float2 wv = cdivz(q, tp);
  if (jj == 0) w_ws[(size_t)wid*8 + ii] = wv;
}

// K5: beam[n,t,f] = sum_c conj(w[n,f,c]) * x[n,c,f,t]; output (n,t,f,2) via LDS transpose
__global__ __launch_bounds__(256) void k5_beam(
    const float* __restrict__ xre, const float* __restrict__ xim,
    const float2* __restrict__ w_ws, float* __restrict__ out)
{
  __shared__ float b_re[32][129];
  __shared__ float b_im[32][129];
  __shared__ float2 w_l[32][8];
  const int n = blockIdx.z;
  const int f0 = blockIdx.y*32;
  const int t0 = blockIdx.x*128;
  const int tid = threadIdx.x;
  {
    const int fl = tid >> 3, c = tid & 7;
    const int f = f0 + fl;
    w_l[fl][c] = (f < F_) ? w_ws[((size_t)n*F_ + f)*8 + c] : make_float2(0.f,0.f);
  }
  __syncthreads();
  const int tq = (tid & 31)*4;
  const int fg = tid >> 5;
  const int t = t0 + tq;
  const bool tok = (t + 3) < T_;
  #pragma unroll
  for (int fi=0; fi<4; ++fi){
    const int fl = fg + fi*8;
    const int f = f0 + fl;
    float4 ar = make_float4(0,0,0,0), ai = make_float4(0,0,0,0);
    if (f < F_ && tok){
      #pragma unroll
      for (int c=0;c<8;++c){
        const size_t base = (((size_t)n*C_ + c)*F_ + f)*T_ + t;
        const float4 xr = *(const float4*)(xre + base);
        const float4 xi = *(const float4*)(xim + base);
        const float2 wv = w_l[fl][c];
        ar.x += wv.x*xr.x + wv.y*xi.x;  ai.x += wv.x*xi.x - wv.y*xr.x;
        ar.y += wv.x*xr.y + wv.y*xi.y;  ai.y += wv.x*xi.y - wv.y*xr.y;
        ar.z += wv.x*xr.z + wv.y*xi.z;  ai.z += wv.x*xi.z - wv.y*xr.z;
        ar.w += wv.x*xr.w + wv.y*xi.w;  ai.w += wv.x*xi.w - wv.y*xr.w;
      }
    }
    b_re[fl][tq+0]=ar.x; b_re[fl][tq+1]=ar.y; b_re[fl][tq+2]=ar.z; b_re[fl][tq+3]=ar.w;
    b_im[fl][tq+0]=ai.x; b_im[fl][tq+1]=ai.y; b_im[fl][tq+2]=ai.z; b_im[fl][tq+3]=ai.w;
  }
  __syncthreads();
  const int fl2 = tid & 31;
  const int tp = tid >> 5;
  const int f2 = f0 + fl2;
  if (f2 < F_){
    #pragma unroll
    for (int k=0;k<16;++k){
      const int tl = tp + k*8;
      const int t2 = t0 + tl;
      if (t2 < T_){
        float2 v = make_float2(b_re[fl2][tl], b_im[fl2][tl]);
        *(float2*)(out + (((size_t)n*T_ + t2)*F_ + f2)*2) = v;
      }
    }
  }
}

extern "C" void kernel_launch(void* const* d_in, const int* in_sizes, int n_in,
                              void* d_out, int out_size, void* d_ws, size_t ws_size,
                              hipStream_t stream)
{
  const float* mask   = (const float*)d_in[0];
  const float* xre    = (const float*)d_in[1];
  const float* xim    = (const float*)d_in[2];
  const float* proj_w = (const float*)d_in[3];
  const float* proj_b = (const float*)d_in[4];
  const float* gvec_w = (const float*)d_in[5];
  const float* gvec_b = (const float*)d_in[6];
  (void)gvec_b;
  float* out = (float*)d_out;
  char* ws = (char*)d_ws;

  size_t o = 0;
  auto alloc = [&](size_t bytes){ size_t r = o; o += (bytes + 255) & ~(size_t)255; return r; };
  float*  m_t  = (float*) (ws + alloc((size_t)N_*F_*T_*4));
  float*  maxv = (float*) (ws + alloc((size_t)N_*F_*4));
  float*  summ = (float*) (ws + alloc((size_t)N_*F_*4));
  float2* Rs   = (float2*)(ws + alloc((size_t)NF_*64*8));
  float2* Rn   = (float2*)(ws + alloc((size_t)NF_*64*8));
  float*  part = (float*) (ws + alloc((size_t)TSPLIT_*NF_*128*4));
  float*  g    = (float*) (ws + alloc((size_t)N_*C_*4));
  float*  feat = (float*) (ws + alloc((size_t)N_*C_*F_*4));
  float2* w_ws = (float2*)(ws + alloc((size_t)NF_*C_*8));

  k1a_stats    <<<dim3(9, N_),        dim3(32,8), 0, stream>>>(mask, maxv, summ);
  k1b_transpose<<<dim3(32, 9, N_),    dim3(32,8), 0, stream>>>(mask, maxv, m_t);
  k2_covar     <<<dim3(NF_, TSPLIT_), dim3(64),   0, stream>>>(xre, xim, m_t, part);
  k2r_reduce   <<<dim3(NF_),          dim3(64),   0, stream>>>(part, summ, Rs, Rn);
  k3a_feat     <<<dim3(N_*C_),        dim3(256),  0, stream>>>(Rs, feat, g);
  k3b_proj     <<<dim3(32, N_*C_),    dim3(256),  0, stream>>>(feat, proj_w, proj_b, gvec_w, g);
  k4_solve     <<<dim3(NF_/4),        dim3(256),  0, stream>>>(Rs, Rn, g, w_ws);
  k5_beam      <<<dim3(8, 9, N_),     dim3(256),  0, stream>>>(xre, xim, w_ws, out);
}

// Round 6
// 273.953 us; speedup vs baseline: 1.3692x; 1.1938x over previous
//
#include <hip/hip_runtime.h>
#include <math.h>

#define N_ 8
#define C_ 8
#define F_ 257
#define T_ 1000
#define ATT_ 512
#define NF_ (N_*F_)
#define TSPLIT_ 4
#define EPSILON_ 1.1920928955078125e-07f
#define EPS_ 1e-5f

__device__ inline float2 cmul(float2 a, float2 b){
  return make_float2(a.x*b.x - a.y*b.y, a.x*b.y + a.y*b.x);
}
__device__ inline float2 crecip(float2 a){
  float id = 1.0f/(a.x*a.x + a.y*a.y);
  return make_float2(a.x*id, -a.y*id);
}
__device__ inline float2 cdivz(float2 a, float2 b){
  float id = 1.0f/(b.x*b.x + b.y*b.y);
  return make_float2((a.x*b.x + a.y*b.y)*id, (a.y*b.x - a.x*b.y)*id);
}
__device__ inline float2 shfl2(float2 v, int src){
  return make_float2(__shfl(v.x, src, 64), __shfl(v.y, src, 64));
}

// K1a: per (n,f): max over t of |mask|, and sum of normalized mask m = mask/(max+eps)
__global__ __launch_bounds__(256) void k1a_stats(
    const float* __restrict__ mask, float* __restrict__ maxv, float* __restrict__ summ)
{
  __shared__ float smx[8][33];
  __shared__ float ssm[8][33];
  const int n = blockIdx.y;
  const int f0 = blockIdx.x*32;
  const int tx = threadIdx.x, ty = threadIdx.y;
  const int f = f0 + tx;
  float mx = 0.f, sm = 0.f;
  if (f < F_){
    for (int t = ty; t < T_; t += 8){
      float v = mask[((size_t)n*T_ + t)*F_ + f];
      mx = fmaxf(mx, fabsf(v));
      sm += v;
    }
  }
  smx[ty][tx] = mx; ssm[ty][tx] = sm;
  __syncthreads();
  if (ty == 0 && f < F_){
    #pragma unroll
    for (int k=1;k<8;++k){ mx = fmaxf(mx, smx[k][tx]); sm += ssm[k][tx]; }
    maxv[n*F_ + f] = mx;
    summ[n*F_ + f] = sm/(mx + EPSILON_);
  }
}

// K1b: normalized mask transpose (n,t,f) -> m_t (n,f,t)
__global__ __launch_bounds__(256) void k1b_transpose(
    const float* __restrict__ mask, const float* __restrict__ maxv, float* __restrict__ m_t)
{
  __shared__ float tile[32][33];
  const int n = blockIdx.z;
  const int f0 = blockIdx.y*32;
  const int t0 = blockIdx.x*32;
  const int tx = threadIdx.x, ty = threadIdx.y;
  const int f = f0 + tx;
  float inv = 0.f;
  if (f < F_) inv = 1.0f/(maxv[n*F_ + f] + EPSILON_);
  #pragma unroll
  for (int k=0;k<4;++k){
    const int tl = ty + 8*k;
    const int t = t0 + tl;
    float v = 0.f;
    if (f < F_ && t < T_) v = mask[((size_t)n*T_ + t)*F_ + f];
    tile[tl][tx] = v*inv;
  }
  __syncthreads();
  #pragma unroll
  for (int k=0;k<4;++k){
    const int fl = ty + 8*k;
    const int f2 = f0 + fl, t2 = t0 + tx;
    if (f2 < F_ && t2 < T_) m_t[((size_t)n*F_ + f2)*T_ + t2] = tile[tx][fl];
  }
}

// K2: one wave per (nf, t-chunk). Global->register loads, Hermitian-triangle accumulate.
__global__ __launch_bounds__(64, 2) void k2_covar(
    const float* __restrict__ xre, const float* __restrict__ xim,
    const float* __restrict__ m_t, float* __restrict__ part)
{
  const int nf = blockIdx.x;
  const int tc = blockIdx.y;
  const int n = nf / F_;
  const int f = nf % F_;
  const int lane = threadIdx.x;
  const int tbase = tc*256;
  const int nt = (tc == 3) ? (T_ - 768) : 256;   // 232 on last chunk, all multiples of 4
  const int tq = lane*4;
  const bool act = tq < nt;

  float xr[8][4], xi[8][4], mm[4];
  if (act){
    const float4 m4 = *(const float4*)(m_t + (size_t)nf*T_ + tbase + tq);
    mm[0]=m4.x; mm[1]=m4.y; mm[2]=m4.z; mm[3]=m4.w;
    #pragma unroll
    for (int c=0;c<8;++c){
      const size_t base = (((size_t)n*C_ + c)*F_ + f)*T_ + tbase + tq;
      const float4 r4 = *(const float4*)(xre + base);
      const float4 i4 = *(const float4*)(xim + base);
      xr[c][0]=r4.x; xr[c][1]=r4.y; xr[c][2]=r4.z; xr[c][3]=r4.w;
      xi[c][0]=i4.x; xi[c][1]=i4.y; xi[c][2]=i4.z; xi[c][3]=i4.w;
    }
  } else {
    mm[0]=mm[1]=mm[2]=mm[3]=0.f;
    #pragma unroll
    for (int c=0;c<8;++c){
      #pragma unroll
      for (int q=0;q<4;++q){ xr[c][q]=0.f; xi[c][q]=0.f; }
    }
  }

  float v[128];
  #pragma unroll
  for (int e=0;e<128;++e) v[e] = 0.f;

  #pragma unroll
  for (int q=0;q<4;++q){
    const float m = mm[q];
    #pragma unroll
    for (int d=0;d<8;++d){
      const float p = xr[d][q]*xr[d][q] + xi[d][q]*xi[d][q];
      v[2*d]   += p;
      v[2*d+1] += m*p;
    }
    #pragma unroll
    for (int a=0;a<8;++a){
      #pragma unroll
      for (int b=a+1;b<8;++b){
        const int e = 16 + 4*(a*(13-a)/2 + b - 1);
        const float pr = xr[a][q]*xr[b][q] + xi[a][q]*xi[b][q];
        const float pi = xi[a][q]*xr[b][q] - xr[a][q]*xi[b][q];
        v[e]   += pr;   v[e+1] += pi;
        v[e+2] += m*pr; v[e+3] += m*pi;
      }
    }
  }

  // paired-fold tree reduce on each 64-entry group (in-place safe).
  #define RSTEP(S, CNT, OFF) \
    _Pragma("unroll") \
    for (int k=0;k<CNT;++k){ \
      const float a_ = v[OFF+2*k], b_ = v[OFF+2*k+1]; \
      const bool hi = (lane & S) != 0; \
      const float mine = hi ? b_ : a_; \
      const float oth  = hi ? a_ : b_; \
      v[OFF+k] = mine + __shfl_xor(oth, S, 64); \
    }
  RSTEP(1,32,0) RSTEP(2,16,0) RSTEP(4,8,0) RSTEP(8,4,0) RSTEP(16,2,0) RSTEP(32,1,0)
  RSTEP(1,32,64) RSTEP(2,16,64) RSTEP(4,8,64) RSTEP(8,4,64) RSTEP(16,2,64) RSTEP(32,1,64)
  #undef RSTEP

  float* pp = part + ((size_t)tc*NF_ + nf)*128;
  pp[lane]      = v[0];
  pp[64 + lane] = v[64];
}

// K2r: sum the 4 t-chunk partials, reconstruct full Hermitian 8x8, normalize -> Rs, Rn.
__global__ __launch_bounds__(64) void k2r_reduce(
    const float* __restrict__ part, const float* __restrict__ summ,
    float2* __restrict__ Rs, float2* __restrict__ Rn)
{
  const int nf = blockIdx.x;
  const int lane = threadIdx.x;
  const int i = lane >> 3, j = lane & 7;
  const int a = (i < j) ? i : j;
  const int b = (i < j) ? j : i;
  const float sgn = (i <= j) ? 1.f : -1.f;
  const int eo = 16 + 4*(a*(13-a)/2 + b - 1);
  float tr=0.f, ti=0.f, sr=0.f, si=0.f;
  #pragma unroll
  for (int tc=0; tc<TSPLIT_; ++tc){
    const float* p = part + ((size_t)tc*NF_ + nf)*128;
    if (i == j){
      tr += p[2*i];
      sr += p[2*i+1];
    } else {
      tr += p[eo];
      ti += sgn*p[eo+1];
      sr += p[eo+2];
      si += sgn*p[eo+3];
    }
  }
  const float sm = summ[nf];
  const float ids = 1.0f/fmaxf(sm, EPSILON_);
  const float idn = 1.0f/fmaxf((float)T_ - sm, EPSILON_);
  Rs[(size_t)nf*64 + lane] = make_float2(sr*ids, si*ids);
  Rn[(size_t)nf*64 + lane] = make_float2((tr-sr)*idn + ((i==j)?EPS_:0.f), (ti-si)*idn);
}

// K3a: feat[nc][f] = |mean offdiag of Rs row c|
__global__ __launch_bounds__(256) void k3a_feat(
    const float2* __restrict__ Rs, float* __restrict__ feat)
{
  const int nc = blockIdx.x;
  const int n = nc >> 3, c = nc & 7;
  const int tid = threadIdx.x;
  for (int f = tid; f < F_; f += 256){
    const float2* row = Rs + (((size_t)n*F_ + f)*8 + c)*8;
    float sr = 0.f, si = 0.f;
    #pragma unroll
    for (int j=0;j<8;++j){ float2 v = row[j]; sr += v.x; si += v.y; }
    float2 d = row[c];
    sr = (sr - d.x)*(1.0f/7.0f);
    si = (si - d.y)*(1.0f/7.0f);
    feat[(size_t)nc*F_ + f] = sqrtf(sr*sr + si*si);
  }
}

// K3b: per-wave partial of sum_a tanh(feat . proj_w[a] + proj_b[a]) * gvec_w[a]
// -> partial3[(chunk*4+wave)*64 + nc], no atomics.
__global__ __launch_bounds__(256) void k3b_proj(
    const float* __restrict__ feat, const float* __restrict__ proj_w,
    const float* __restrict__ proj_b, const float* __restrict__ gvec_w,
    float* __restrict__ partial3)
{
  const int nc = blockIdx.y;
  const int tid = threadIdx.x;
  const int wave = tid >> 6, lane = tid & 63;
  const int a0 = blockIdx.x*16 + wave*4;
  float acc0 = 0.f, acc1 = 0.f, acc2 = 0.f, acc3 = 0.f;
  const float* fr = feat + (size_t)nc*F_;
  const float* w0 = proj_w + (size_t)(a0+0)*F_;
  const float* w1 = proj_w + (size_t)(a0+1)*F_;
  const float* w2 = proj_w + (size_t)(a0+2)*F_;
  const float* w3 = proj_w + (size_t)(a0+3)*F_;
  for (int fi = lane; fi < F_; fi += 64){
    const float fv = fr[fi];
    acc0 += fv*w0[fi];
    acc1 += fv*w1[fi];
    acc2 += fv*w2[fi];
    acc3 += fv*w3[fi];
  }
  #pragma unroll
  for (int s=1;s<64;s<<=1){
    acc0 += __shfl_xor(acc0, s, 64);
    acc1 += __shfl_xor(acc1, s, 64);
    acc2 += __shfl_xor(acc2, s, 64);
    acc3 += __shfl_xor(acc3, s, 64);
  }
  if (lane == 0){
    float v = tanhf(acc0 + proj_b[a0+0])*gvec_w[a0+0]
            + tanhf(acc1 + proj_b[a0+1])*gvec_w[a0+1]
            + tanhf(acc2 + proj_b[a0+2])*gvec_w[a0+2]
            + tanhf(acc3 + proj_b[a0+3])*gvec_w[a0+3];
    partial3[(size_t)(blockIdx.x*4 + wave)*64 + nc] = v;
  }
}

// K3c: g[nc] = sum over 128 wave-partials (coalesced per iteration). One wave total.
__global__ __launch_bounds__(64) void k3c_gsum(
    const float* __restrict__ partial3, float* __restrict__ g)
{
  const int lane = threadIdx.x;
  float s = 0.f;
  #pragma unroll
  for (int p=0;p<128;++p) s += partial3[(size_t)p*64 + lane];
  g[lane] = s;
}

// K4: one wave per (n,f): softmax(u), invert Rn, w = Rn^-1 (Rs u) / (tr(Rn^-1 Rs)+EPS)
__global__ __launch_bounds__(256) void k4_solve(
    const float2* __restrict__ Rs, const float2* __restrict__ Rn,
    const float* __restrict__ g, float2* __restrict__ w_ws)
{
  const int tid = threadIdx.x;
  const int wid = blockIdx.x*4 + (tid >> 6);
  const int lane = tid & 63;
  const int ii = lane >> 3, jj = lane & 7;
  const int n = wid / F_;
  float2 A = Rn[(size_t)wid*64 + lane];
  float2 R = Rs[(size_t)wid*64 + lane];
  float gv = g[n*C_ + jj];
  float mx = gv;
  #pragma unroll
  for (int s=1;s<8;s<<=1) mx = fmaxf(mx, __shfl_xor(mx, s, 64));
  float e = expf(gv - mx);
  float es = e;
  #pragma unroll
  for (int s=1;s<8;s<<=1) es += __shfl_xor(es, s, 64);
  const float u = e / es;
  #pragma unroll
  for (int k=0;k<8;++k){
    float2 piv    = shfl2(A, k*9);
    float2 oldAkj = shfl2(A, k*8 + jj);
    float2 dum    = shfl2(A, ii*8 + k);
    float2 pinv = crecip(piv);
    float2 newk = (jj==k) ? pinv : cmul(oldAkj, pinv);
    if (ii == k){
      A = newk;
    } else {
      float2 b = (jj==k) ? make_float2(0.f,0.f) : A;
      float2 t = cmul(newk, dum);
      A = make_float2(b.x - t.x, b.y - t.y);
    }
  }
  float2 v = make_float2(R.x*u, R.y*u);
  #pragma unroll
  for (int s=1;s<8;s<<=1){ v.x += __shfl_xor(v.x, s, 64); v.y += __shfl_xor(v.y, s, 64); }
  float2 Rt = shfl2(R, jj*8 + ii);
  float2 tp = cmul(A, Rt);
  #pragma unroll
  for (int s=1;s<64;s<<=1){ tp.x += __shfl_xor(tp.x, s, 64); tp.y += __shfl_xor(tp.y, s, 64); }
  tp.x += EPS_;
  float2 vj = shfl2(v, jj*8);
  float2 q = cmul(A, vj);
  #pragma unroll
  for (int s=1;s<8;s<<=1){ q.x += __shfl_xor(q.x, s, 64); q.y += __shfl_xor(q.y, s, 64); }
  float2 wv = cdivz(q, tp);
  if (jj == 0) w_ws[(size_t)wid*8 + ii] = wv;
}

// K5: beam[n,t,f] = sum_c conj(w[n,f,c]) * x[n,c,f,t]; output (n,t,f,2) via LDS transpose
__global__ __launch_bounds__(256) void k5_beam(
    const float* __restrict__ xre, const float* __restrict__ xim,
    const float2* __restrict__ w_ws, float* __restrict__ out)
{
  __shared__ float b_re[32][129];
  __shared__ float b_im[32][129];
  __shared__ float2 w_l[32][8];
  const int n = blockIdx.z;
  const int f0 = blockIdx.y*32;
  const int t0 = blockIdx.x*128;
  const int tid = threadIdx.x;
  {
    const int fl = tid >> 3, c = tid & 7;
    const int f = f0 + fl;
    w_l[fl][c] = (f < F_) ? w_ws[((size_t)n*F_ + f)*8 + c] : make_float2(0.f,0.f);
  }
  __syncthreads();
  const int tq = (tid & 31)*4;
  const int fg = tid >> 5;
  const int t = t0 + tq;
  const bool tok = (t + 3) < T_;
  #pragma unroll
  for (int fi=0; fi<4; ++fi){
    const int fl = fg + fi*8;
    const int f = f0 + fl;
    float4 ar = make_float4(0,0,0,0), ai = make_float4(0,0,0,0);
    if (f < F_ && tok){
      #pragma unroll
      for (int c=0;c<8;++c){
        const size_t base = (((size_t)n*C_ + c)*F_ + f)*T_ + t;
        const float4 xr = *(const float4*)(xre + base);
        const float4 xi = *(const float4*)(xim + base);
        const float2 wv = w_l[fl][c];
        ar.x += wv.x*xr.x + wv.y*xi.x;  ai.x += wv.x*xi.x - wv.y*xr.x;
        ar.y += wv.x*xr.y + wv.y*xi.y;  ai.y += wv.x*xi.y - wv.y*xr.y;
        ar.z += wv.x*xr.z + wv.y*xi.z;  ai.z += wv.x*xi.z - wv.y*xr.z;
        ar.w += wv.x*xr.w + wv.y*xi.w;  ai.w += wv.x*xi.w - wv.y*xr.w;
      }
    }
    b_re[fl][tq+0]=ar.x; b_re[fl][tq+1]=ar.y; b_re[fl][tq+2]=ar.z; b_re[fl][tq+3]=ar.w;
    b_im[fl][tq+0]=ai.x; b_im[fl][tq+1]=ai.y; b_im[fl][tq+2]=ai.z; b_im[fl][tq+3]=ai.w;
  }
  __syncthreads();
  const int fl2 = tid & 31;
  const int tp = tid >> 5;
  const int f2 = f0 + fl2;
  if (f2 < F_){
    #pragma unroll
    for (int k=0;k<16;++k){
      const int tl = tp + k*8;
      const int t2 = t0 + tl;
      if (t2 < T_){
        float2 v = make_float2(b_re[fl2][tl], b_im[fl2][tl]);
        *(float2*)(out + (((size_t)n*T_ + t2)*F_ + f2)*2) = v;
      }
    }
  }
}

extern "C" void kernel_launch(void* const* d_in, const int* in_sizes, int n_in,
                              void* d_out, int out_size, void* d_ws, size_t ws_size,
                              hipStream_t stream)
{
  const float* mask   = (const float*)d_in[0];
  const float* xre    = (const float*)d_in[1];
  const float* xim    = (const float*)d_in[2];
  const float* proj_w = (const float*)d_in[3];
  const float* proj_b = (const float*)d_in[4];
  const float* gvec_w = (const float*)d_in[5];
  const float* gvec_b = (const float*)d_in[6];
  (void)gvec_b;
  float* out = (float*)d_out;
  char* ws = (char*)d_ws;

  size_t o = 0;
  auto alloc = [&](size_t bytes){ size_t r = o; o += (bytes + 255) & ~(size_t)255; return r; };
  float*  m_t   = (float*) (ws + alloc((size_t)N_*F_*T_*4));
  float*  maxv  = (float*) (ws + alloc((size_t)N_*F_*4));
  float*  summ  = (float*) (ws + alloc((size_t)N_*F_*4));
  float2* Rs    = (float2*)(ws + alloc((size_t)NF_*64*8));
  float2* Rn    = (float2*)(ws + alloc((size_t)NF_*64*8));
  float*  part  = (float*) (ws + alloc((size_t)TSPLIT_*NF_*128*4));
  float*  g     = (float*) (ws + alloc((size_t)N_*C_*4));
  float*  feat  = (float*) (ws + alloc((size_t)N_*C_*F_*4));
  float*  part3 = (float*) (ws + alloc((size_t)128*64*4));
  float2* w_ws  = (float2*)(ws + alloc((size_t)NF_*C_*8));

  k1a_stats    <<<dim3(9, N_),        dim3(32,8), 0, stream>>>(mask, maxv, summ);
  k1b_transpose<<<dim3(32, 9, N_),    dim3(32,8), 0, stream>>>(mask, maxv, m_t);
  k2_covar     <<<dim3(NF_, TSPLIT_), dim3(64),   0, stream>>>(xre, xim, m_t, part);
  k2r_reduce   <<<dim3(NF_),          dim3(64),   0, stream>>>(part, summ, Rs, Rn);
  k3a_feat     <<<dim3(N_*C_),        dim3(256),  0, stream>>>(Rs, feat);
  k3b_proj     <<<dim3(32, N_*C_),    dim3(256),  0, stream>>>(feat, proj_w, proj_b, gvec_w, part3);
  k3c_gsum     <<<dim3(1),            dim3(64),   0, stream>>>(part3, g);
  k4_solve     <<<dim3(NF_/4),        dim3(256),  0, stream>>>(Rs, Rn, g, w_ws);
  k5_beam      <<<dim3(8, 9, N_),     dim3(256),  0, stream>>>(xre, xim, w_ws, out);
}

// Round 8
// 235.025 us; speedup vs baseline: 1.5960x; 1.1656x over previous
//
#include <hip/hip_runtime.h>
#include <math.h>

#define N_ 8
#define C_ 8
#define F_ 257
#define T_ 1000
#define ATT_ 512
#define NF_ (N_*F_)
#define TSPLIT_ 4
#define TCHUNKS1_ 32
#define EPSILON_ 1.1920928955078125e-07f
#define EPS_ 1e-5f

__device__ inline float2 cmul(float2 a, float2 b){
  return make_float2(a.x*b.x - a.y*b.y, a.x*b.y + a.y*b.x);
}
__device__ inline float2 crecip(float2 a){
  float id = 1.0f/(a.x*a.x + a.y*a.y);
  return make_float2(a.x*id, -a.y*id);
}
__device__ inline float2 cdivz(float2 a, float2 b){
  float id = 1.0f/(b.x*b.x + b.y*b.y);
  return make_float2((a.x*b.x + a.y*b.y)*id, (a.y*b.x - a.x*b.y)*id);
}
__device__ inline float2 shfl2(float2 v, int src){
  return make_float2(__shfl(v.x, src, 64), __shfl(v.y, src, 64));
}

// K1: fused transpose + partial stats. Raw mask (n,t,f) -> mask_t (n,f,t);
// per 32-t tile: partial max|mask| and raw sum per f -> pmax/psum[chunk][nf].
// Normalization by 1/(max+eps) is deferred to k2r (exact algebra).
__global__ __launch_bounds__(256) void k1_fused(
    const float* __restrict__ mask, float* __restrict__ mask_t,
    float* __restrict__ pmax, float* __restrict__ psum)
{
  __shared__ float tile[32][33];
  __shared__ float smx[8][33];
  __shared__ float ssm[8][33];
  const int n = blockIdx.z;
  const int f0 = blockIdx.y*32;
  const int t0 = blockIdx.x*32;
  const int tx = threadIdx.x, ty = threadIdx.y;
  const int f = f0 + tx;
  float mx = 0.f, sm = 0.f;
  #pragma unroll
  for (int k=0;k<4;++k){
    const int tl = ty + 8*k;
    const int t = t0 + tl;
    float v = 0.f;
    if (f < F_ && t < T_) v = mask[((size_t)n*T_ + t)*F_ + f];
    tile[tl][tx] = v;
    mx = fmaxf(mx, fabsf(v));   // zeros for OOB can't exceed the true max (mask >= 0)
    sm += v;
  }
  smx[ty][tx] = mx; ssm[ty][tx] = sm;
  __syncthreads();
  #pragma unroll
  for (int k=0;k<4;++k){
    const int fl = ty + 8*k;
    const int f2 = f0 + fl, t2 = t0 + tx;
    if (f2 < F_ && t2 < T_) mask_t[((size_t)n*F_ + f2)*T_ + t2] = tile[tx][fl];
  }
  if (ty == 0 && f < F_){
    #pragma unroll
    for (int k=1;k<8;++k){ mx = fmaxf(mx, smx[k][tx]); sm += ssm[k][tx]; }
    pmax[(size_t)blockIdx.x*NF_ + n*F_ + f] = mx;
    psum[(size_t)blockIdx.x*NF_ + n*F_ + f] = sm;
  }
}

// K1r: fold 32 chunk-partials -> maxv[nf], summ[nf] (= rawsum/(max+eps) = sum of normalized m)
__global__ __launch_bounds__(256) void k1r_reduce(
    const float* __restrict__ pmax, const float* __restrict__ psum,
    float* __restrict__ maxv, float* __restrict__ summ)
{
  const int idx = blockIdx.x*256 + threadIdx.x;
  if (idx >= NF_) return;
  float mx = 0.f, sm = 0.f;
  #pragma unroll
  for (int c=0;c<TCHUNKS1_;++c){
    mx = fmaxf(mx, pmax[(size_t)c*NF_ + idx]);
    sm += psum[(size_t)c*NF_ + idx];
  }
  maxv[idx] = mx;
  summ[idx] = sm/(mx + EPSILON_);
}

// K2: one wave per (nf, t-chunk). Global->register loads, Hermitian-triangle accumulate.
// Masked accumulators use the RAW mask; scaled by inv in k2r.
__global__ __launch_bounds__(64, 2) void k2_covar(
    const float* __restrict__ xre, const float* __restrict__ xim,
    const float* __restrict__ mask_t, float* __restrict__ part)
{
  const int nf = blockIdx.x;
  const int tc = blockIdx.y;
  const int n = nf / F_;
  const int f = nf % F_;
  const int lane = threadIdx.x;
  const int tbase = tc*256;
  const int nt = (tc == 3) ? (T_ - 768) : 256;   // 232 on last chunk, all multiples of 4
  const int tq = lane*4;
  const bool act = tq < nt;

  float xr[8][4], xi[8][4], mm[4];
  if (act){
    const float4 m4 = *(const float4*)(mask_t + (size_t)nf*T_ + tbase + tq);
    mm[0]=m4.x; mm[1]=m4.y; mm[2]=m4.z; mm[3]=m4.w;
    #pragma unroll
    for (int c=0;c<8;++c){
      const size_t base = (((size_t)n*C_ + c)*F_ + f)*T_ + tbase + tq;
      const float4 r4 = *(const float4*)(xre + base);
      const float4 i4 = *(const float4*)(xim + base);
      xr[c][0]=r4.x; xr[c][1]=r4.y; xr[c][2]=r4.z; xr[c][3]=r4.w;
      xi[c][0]=i4.x; xi[c][1]=i4.y; xi[c][2]=i4.z; xi[c][3]=i4.w;
    }
  } else {
    mm[0]=mm[1]=mm[2]=mm[3]=0.f;
    #pragma unroll
    for (int c=0;c<8;++c){
      #pragma unroll
      for (int q=0;q<4;++q){ xr[c][q]=0.f; xi[c][q]=0.f; }
    }
  }

  float v[128];
  #pragma unroll
  for (int e=0;e<128;++e) v[e] = 0.f;

  #pragma unroll
  for (int q=0;q<4;++q){
    const float m = mm[q];
    #pragma unroll
    for (int d=0;d<8;++d){
      const float p = xr[d][q]*xr[d][q] + xi[d][q]*xi[d][q];
      v[2*d]   += p;
      v[2*d+1] += m*p;
    }
    #pragma unroll
    for (int a=0;a<8;++a){
      #pragma unroll
      for (int b=a+1;b<8;++b){
        const int e = 16 + 4*(a*(13-a)/2 + b - 1);
        const float pr = xr[a][q]*xr[b][q] + xi[a][q]*xi[b][q];
        const float pi = xi[a][q]*xr[b][q] - xr[a][q]*xi[b][q];
        v[e]   += pr;   v[e+1] += pi;
        v[e+2] += m*pr; v[e+3] += m*pi;
      }
    }
  }

  // paired-fold tree reduce on each 64-entry group (in-place safe).
  #define RSTEP(S, CNT, OFF) \
    _Pragma("unroll") \
    for (int k=0;k<CNT;++k){ \
      const float a_ = v[OFF+2*k], b_ = v[OFF+2*k+1]; \
      const bool hi = (lane & S) != 0; \
      const float mine = hi ? b_ : a_; \
      const float oth  = hi ? a_ : b_; \
      v[OFF+k] = mine + __shfl_xor(oth, S, 64); \
    }
  RSTEP(1,32,0) RSTEP(2,16,0) RSTEP(4,8,0) RSTEP(8,4,0) RSTEP(16,2,0) RSTEP(32,1,0)
  RSTEP(1,32,64) RSTEP(2,16,64) RSTEP(4,8,64) RSTEP(8,4,64) RSTEP(16,2,64) RSTEP(32,1,64)
  #undef RSTEP

  float* pp = part + ((size_t)tc*NF_ + nf)*128;
  pp[lane]      = v[0];
  pp[64 + lane] = v[64];
}

// K2r: sum t-chunk partials, apply deferred inv-max scale, normalize -> Rs, Rn.
__global__ __launch_bounds__(64) void k2r_reduce(
    const float* __restrict__ part, const float* __restrict__ maxv,
    const float* __restrict__ summ,
    float2* __restrict__ Rs, float2* __restrict__ Rn)
{
  const int nf = blockIdx.x;
  const int lane = threadIdx.x;
  const int i = lane >> 3, j = lane & 7;
  const int a = (i < j) ? i : j;
  const int b = (i < j) ? j : i;
  const float sgn = (i <= j) ? 1.f : -1.f;
  const int eo = 16 + 4*(a*(13-a)/2 + b - 1);
  float tr=0.f, ti=0.f, sr=0.f, si=0.f;
  #pragma unroll
  for (int tc=0; tc<TSPLIT_; ++tc){
    const float* p = part + ((size_t)tc*NF_ + nf)*128;
    if (i == j){
      tr += p[2*i];
      sr += p[2*i+1];
    } else {
      tr += p[eo];
      ti += sgn*p[eo+1];
      sr += p[eo+2];
      si += sgn*p[eo+3];
    }
  }
  const float inv = 1.0f/(maxv[nf] + EPSILON_);
  sr *= inv; si *= inv;                       // raw-masked -> normalized-masked
  const float sm = summ[nf];
  const float ids = 1.0f/fmaxf(sm, EPSILON_);
  const float idn = 1.0f/fmaxf((float)T_ - sm, EPSILON_);
  Rs[(size_t)nf*64 + lane] = make_float2(sr*ids, si*ids);
  Rn[(size_t)nf*64 + lane] = make_float2((tr-sr)*idn + ((i==j)?EPS_:0.f), (ti-si)*idn);
}

// K3a: feat[nc][f] = |mean offdiag of Rs row c|
__global__ __launch_bounds__(256) void k3a_feat(
    const float2* __restrict__ Rs, float* __restrict__ feat)
{
  const int nc = blockIdx.x;
  const int n = nc >> 3, c = nc & 7;
  const int tid = threadIdx.x;
  for (int f = tid; f < F_; f += 256){
    const float2* row = Rs + (((size_t)n*F_ + f)*8 + c)*8;
    float sr = 0.f, si = 0.f;
    #pragma unroll
    for (int j=0;j<8;++j){ float2 v = row[j]; sr += v.x; si += v.y; }
    float2 d = row[c];
    sr = (sr - d.x)*(1.0f/7.0f);
    si = (si - d.y)*(1.0f/7.0f);
    feat[(size_t)nc*F_ + f] = sqrtf(sr*sr + si*si);
  }
}

// K3b: per-wave partial of sum_a tanh(feat . proj_w[a] + proj_b[a]) * gvec_w[a]
__global__ __launch_bounds__(256) void k3b_proj(
    const float* __restrict__ feat, const float* __restrict__ proj_w,
    const float* __restrict__ proj_b, const float* __restrict__ gvec_w,
    float* __restrict__ partial3)
{
  const int nc = blockIdx.y;
  const int tid = threadIdx.x;
  const int wave = tid >> 6, lane = tid & 63;
  const int a0 = blockIdx.x*16 + wave*4;
  float acc0 = 0.f, acc1 = 0.f, acc2 = 0.f, acc3 = 0.f;
  const float* fr = feat + (size_t)nc*F_;
  const float* w0 = proj_w + (size_t)(a0+0)*F_;
  const float* w1 = proj_w + (size_t)(a0+1)*F_;
  const float* w2 = proj_w + (size_t)(a0+2)*F_;
  const float* w3 = proj_w + (size_t)(a0+3)*F_;
  for (int fi = lane; fi < F_; fi += 64){
    const float fv = fr[fi];
    acc0 += fv*w0[fi];
    acc1 += fv*w1[fi];
    acc2 += fv*w2[fi];
    acc3 += fv*w3[fi];
  }
  #pragma unroll
  for (int s=1;s<64;s<<=1){
    acc0 += __shfl_xor(acc0, s, 64);
    acc1 += __shfl_xor(acc1, s, 64);
    acc2 += __shfl_xor(acc2, s, 64);
    acc3 += __shfl_xor(acc3, s, 64);
  }
  if (lane == 0){
    float v = tanhf(acc0 + proj_b[a0+0])*gvec_w[a0+0]
            + tanhf(acc1 + proj_b[a0+1])*gvec_w[a0+1]
            + tanhf(acc2 + proj_b[a0+2])*gvec_w[a0+2]
            + tanhf(acc3 + proj_b[a0+3])*gvec_w[a0+3];
    partial3[(size_t)(blockIdx.x*4 + wave)*64 + nc] = v;
  }
}

// K3c: g[nc] = sum over 128 wave-partials. One wave total.
__global__ __launch_bounds__(64) void k3c_gsum(
    const float* __restrict__ partial3, float* __restrict__ g)
{
  const int lane = threadIdx.x;
  float s = 0.f;
  #pragma unroll
  for (int p=0;p<128;++p) s += partial3[(size_t)p*64 + lane];
  g[lane] = s;
}

// K4: one wave per (n,f): softmax(u), invert Rn, w = Rn^-1 (Rs u) / (tr(Rn^-1 Rs)+EPS)
__global__ __launch_bounds__(256) void k4_solve(
    const float2* __restrict__ Rs, const float2* __restrict__ Rn,
    const float* __restrict__ g, float2* __restrict__ w_ws)
{
  const int tid = threadIdx.x;
  const int wid = blockIdx.x*4 + (tid >> 6);
  const int lane = tid & 63;
  const int ii = lane >> 3, jj = lane & 7;
  const int n = wid / F_;
  float2 A = Rn[(size_t)wid*64 + lane];
  float2 R = Rs[(size_t)wid*64 + lane];
  float gv = g[n*C_ + jj];
  float mx = gv;
  #pragma unroll
  for (int s=1;s<8;s<<=1) mx = fmaxf(mx, __shfl_xor(mx, s, 64));
  float e = expf(gv - mx);
  float es = e;
  #pragma unroll
  for (int s=1;s<8;s<<=1) es += __shfl_xor(es, s, 64);
  const float u = e / es;
  #pragma unroll
  for (int k=0;k<8;++k){
    float2 piv    = shfl2(A, k*9);
    float2 oldAkj = shfl2(A, k*8 + jj);
    float2 dum    = shfl2(A, ii*8 + k);
    float2 pinv = crecip(piv);
    float2 newk = (jj==k) ? pinv : cmul(oldAkj, pinv);
    if (ii == k){
      A = newk;
    } else {
      float2 b = (jj==k) ? make_float2(0.f,0.f) : A;
      float2 t = cmul(newk, dum);
      A = make_float2(b.x - t.x, b.y - t.y);
    }
  }
  float2 v = make_float2(R.x*u, R.y*u);
  #pragma unroll
  for (int s=1;s<8;s<<=1){ v.x += __shfl_xor(v.x, s, 64); v.y += __shfl_xor(v.y, s, 64); }
  float2 Rt = shfl2(R, jj*8 + ii);
  float2 tp = cmul(A, Rt);
  #pragma unroll
  for (int s=1;s<64;s<<=1){ tp.x += __shfl_xor(tp.x, s, 64); tp.y += __shfl_xor(tp.y, s, 64); }
  tp.x += EPS_;
  float2 vj = shfl2(v, jj*8);
  float2 q = cmul(A, vj);
  #pragma unroll
  for (int s=1;s<8;s<<=1){ q.x += __shfl_xor(q.x, s, 64); q.y += __shfl_xor(q.y, s, 64); }
  float2 wv = cdivz(q, tp);
  if (jj == 0) w_ws[(size_t)wid*8 + ii] = wv;
}

// K5: beam[n,t,f] = sum_c conj(w[n,f,c]) * x[n,c,f,t]; output (n,t,f,2) via LDS transpose
__global__ __launch_bounds__(256) void k5_beam(
    const float* __restrict__ xre, const float* __restrict__ xim,
    const float2* __restrict__ w_ws, float* __restrict__ out)
{
  __shared__ float b_re[32][129];
  __shared__ float b_im[32][129];
  __shared__ float2 w_l[32][8];
  const int n = blockIdx.z;
  const int f0 = blockIdx.y*32;
  const int t0 = blockIdx.x*128;
  const int tid = threadIdx.x;
  {
    const int fl = tid >> 3, c = tid & 7;
    const int f = f0 + fl;
    w_l[fl][c] = (f < F_) ? w_ws[((size_t)n*F_ + f)*8 + c] : make_float2(0.f,0.f);
  }
  __syncthreads();
  const int tq = (tid & 31)*4;
  const int fg = tid >> 5;
  const int t = t0 + tq;
  const bool tok = (t + 3) < T_;
  #pragma unroll
  for (int fi=0; fi<4; ++fi){
    const int fl = fg + fi*8;
    const int f = f0 + fl;
    float4 ar = make_float4(0,0,0,0), ai = make_float4(0,0,0,0);
    if (f < F_ && tok){
      #pragma unroll
      for (int c=0;c<8;++c){
        const size_t base = (((size_t)n*C_ + c)*F_ + f)*T_ + t;
        const float4 xr = *(const float4*)(xre + base);
        const float4 xi = *(const float4*)(xim + base);
        const float2 wv = w_l[fl][c];
        ar.x += wv.x*xr.x + wv.y*xi.x;  ai.x += wv.x*xi.x - wv.y*xr.x;
        ar.y += wv.x*xr.y + wv.y*xi.y;  ai.y += wv.x*xi.y - wv.y*xr.y;
        ar.z += wv.x*xr.z + wv.y*xi.z;  ai.z += wv.x*xi.z - wv.y*xr.z;
        ar.w += wv.x*xr.w + wv.y*xi.w;  ai.w += wv.x*xi.w - wv.y*xr.w;
      }
    }
    b_re[fl][tq+0]=ar.x; b_re[fl][tq+1]=ar.y; b_re[fl][tq+2]=ar.z; b_re[fl][tq+3]=ar.w;
    b_im[fl][tq+0]=ai.x; b_im[fl][tq+1]=ai.y; b_im[fl][tq+2]=ai.z; b_im[fl][tq+3]=ai.w;
  }
  __syncthreads();
  const int fl2 = tid & 31;
  const int tp = tid >> 5;
  const int f2 = f0 + fl2;
  if (f2 < F_){
    #pragma unroll
    for (int k=0;k<16;++k){
      const int tl = tp + k*8;
      const int t2 = t0 + tl;
      if (t2 < T_){
        float2 v = make_float2(b_re[fl2][tl], b_im[fl2][tl]);
        *(float2*)(out + (((size_t)n*T_ + t2)*F_ + f2)*2) = v;
      }
    }
  }
}

extern "C" void kernel_launch(void* const* d_in, const int* in_sizes, int n_in,
                              void* d_out, int out_size, void* d_ws, size_t ws_size,
                              hipStream_t stream)
{
  const float* mask   = (const float*)d_in[0];
  const float* xre    = (const float*)d_in[1];
  const float* xim    = (const float*)d_in[2];
  const float* proj_w = (const float*)d_in[3];
  const float* proj_b = (const float*)d_in[4];
  const float* gvec_w = (const float*)d_in[5];
  const float* gvec_b = (const float*)d_in[6];
  (void)gvec_b;
  float* out = (float*)d_out;
  char* ws = (char*)d_ws;

  size_t o = 0;
  auto alloc = [&](size_t bytes){ size_t r = o; o += (bytes + 255) & ~(size_t)255; return r; };
  float*  mask_t = (float*) (ws + alloc((size_t)N_*F_*T_*4));
  float*  maxv   = (float*) (ws + alloc((size_t)NF_*4));
  float*  summ   = (float*) (ws + alloc((size_t)NF_*4));
  float*  pmax   = (float*) (ws + alloc((size_t)TCHUNKS1_*NF_*4));
  float*  psum   = (float*) (ws + alloc((size_t)TCHUNKS1_*NF_*4));
  float2* Rs     = (float2*)(ws + alloc((size_t)NF_*64*8));
  float2* Rn     = (float2*)(ws + alloc((size_t)NF_*64*8));
  float*  part   = (float*) (ws + alloc((size_t)TSPLIT_*NF_*128*4));
  float*  g      = (float*) (ws + alloc((size_t)N_*C_*4));
  float*  feat   = (float*) (ws + alloc((size_t)N_*C_*F_*4));
  float*  part3  = (float*) (ws + alloc((size_t)128*64*4));
  float2* w_ws   = (float2*)(ws + alloc((size_t)NF_*C_*8));

  k1_fused   <<<dim3(TCHUNKS1_, 9, N_), dim3(32,8), 0, stream>>>(mask, mask_t, pmax, psum);
  k1r_reduce <<<dim3((NF_+255)/256),    dim3(256),  0, stream>>>(pmax, psum, maxv, summ);
  k2_covar   <<<dim3(NF_, TSPLIT_),     dim3(64),   0, stream>>>(xre, xim, mask_t, part);
  k2r_reduce <<<dim3(NF_),              dim3(64),   0, stream>>>(part, maxv, summ, Rs, Rn);
  k3a_feat   <<<dim3(N_*C_),            dim3(256),  0, stream>>>(Rs, feat);
  k3b_proj   <<<dim3(32, N_*C_),        dim3(256),  0, stream>>>(feat, proj_w, proj_b, gvec_w, part3);
  k3c_gsum   <<<dim3(1),                dim3(64),   0, stream>>>(part3, g);
  k4_solve   <<<dim3(NF_/4),            dim3(256),  0, stream>>>(Rs, Rn, g, w_ws);
  k5_beam    <<<dim3(8, 9, N_),         dim3(256),  0, stream>>>(xre, xim, w_ws, out);
}